// Round 1
// baseline (20602.693 us; speedup 1.0000x reference)
//
#include <hip/hip_runtime.h>

#define SEQ 512
#define BATCH 32
#define NTAG 12
#define STOP_TAG 11
#define SCAN_WGS 64

static __device__ __forceinline__ float sigm(float x) {
  return 1.0f / (1.0f + __expf(-x));
}
static __device__ __forceinline__ float tanh_fast(float x) {
  // exact identity: tanh(x) = 1 - 2/(exp(2x)+1); error only from __expf ulp
  return 1.0f - 2.0f / (1.0f + __expf(2.0f * x));
}

// ---------------- embedding gather: x0[s*32+b][e] = emb[inputs[b][s]][e] ----------------
__global__ __launch_bounds__(64) void embed_kernel(const int* __restrict__ inputs,
                                                   const float* __restrict__ emb,
                                                   float* __restrict__ x0) {
  const int sb = blockIdx.x;          // s*32 + b
  const int s = sb >> 5, b = sb & 31;
  const int tok = inputs[b * SEQ + s];
  const float4* src = (const float4*)(emb + (size_t)tok * 256);
  float4* dst = (float4*)(x0 + (size_t)sb * 256);
  dst[threadIdx.x] = src[threadIdx.x];
}

// ---------------- generic fp32 GEMM: C[M][N] = A[M][K] @ W[N][K]^T (+b1+b2) ----------------
// 64x64 tile, 256 threads, 4x4 per thread. M % 64 == 0 assumed; N may be ragged.
__global__ __launch_bounds__(256) void gemm_nt(const float* __restrict__ A,
                                               const float* __restrict__ W,
                                               const float* __restrict__ b1,
                                               const float* __restrict__ b2,
                                               float* __restrict__ C,
                                               int M, int N, int K, int ldc) {
  __shared__ float aT[16][68];
  __shared__ float wT[16][68];
  const int tid = threadIdx.x;
  const int bm = blockIdx.x * 64;
  const int bn = blockIdx.y * 64;
  const int tm = ((tid >> 4) & 15) << 2;
  const int tn = (tid & 15) << 2;
  const int lr = tid >> 2;
  const int lk = (tid & 3) << 2;
  const bool wok = (bn + lr) < N;
  float acc00 = 0.f, acc01 = 0.f, acc02 = 0.f, acc03 = 0.f;
  float acc10 = 0.f, acc11 = 0.f, acc12 = 0.f, acc13 = 0.f;
  float acc20 = 0.f, acc21 = 0.f, acc22 = 0.f, acc23 = 0.f;
  float acc30 = 0.f, acc31 = 0.f, acc32 = 0.f, acc33 = 0.f;
  for (int k0 = 0; k0 < K; k0 += 16) {
    float4 av = *(const float4*)(A + (size_t)(bm + lr) * K + k0 + lk);
    float4 wv = make_float4(0.f, 0.f, 0.f, 0.f);
    if (wok) wv = *(const float4*)(W + (size_t)(bn + lr) * K + k0 + lk);
    aT[lk + 0][lr] = av.x; aT[lk + 1][lr] = av.y; aT[lk + 2][lr] = av.z; aT[lk + 3][lr] = av.w;
    wT[lk + 0][lr] = wv.x; wT[lk + 1][lr] = wv.y; wT[lk + 2][lr] = wv.z; wT[lk + 3][lr] = wv.w;
    __syncthreads();
#pragma unroll
    for (int k = 0; k < 16; ++k) {
      float4 a4 = *(const float4*)&aT[k][tm];
      float4 w4 = *(const float4*)&wT[k][tn];
      acc00 += a4.x * w4.x; acc01 += a4.x * w4.y; acc02 += a4.x * w4.z; acc03 += a4.x * w4.w;
      acc10 += a4.y * w4.x; acc11 += a4.y * w4.y; acc12 += a4.y * w4.z; acc13 += a4.y * w4.w;
      acc20 += a4.z * w4.x; acc21 += a4.z * w4.y; acc22 += a4.z * w4.z; acc23 += a4.z * w4.w;
      acc30 += a4.w * w4.x; acc31 += a4.w * w4.y; acc32 += a4.w * w4.z; acc33 += a4.w * w4.w;
    }
    __syncthreads();
  }
  float r[4][4] = {{acc00, acc01, acc02, acc03},
                   {acc10, acc11, acc12, acc13},
                   {acc20, acc21, acc22, acc23},
                   {acc30, acc31, acc32, acc33}};
#pragma unroll
  for (int i = 0; i < 4; ++i) {
#pragma unroll
    for (int j = 0; j < 4; ++j) {
      int n = bn + tn + j;
      if (n < N) {
        float v = r[i][j];
        if (b1) v += b1[n];
        if (b2) v += b2[n];
        C[(size_t)(bm + tm + i) * ldc + n] = v;
      }
    }
  }
}

// ---------------- persistent BiLSTM scan ----------------
// grid = 128: wg<64 -> forward, wg>=64 -> backward. Each WG owns 4 hidden units
// (16 z-columns). h exchanged through global hs via agent-scope atomics;
// per-direction counter barrier between steps.
__global__ __launch_bounds__(256) void lstm_scan(const float* __restrict__ pre_f,
                                                 const float* __restrict__ pre_b,
                                                 const float* __restrict__ whh_f,
                                                 const float* __restrict__ whh_b,
                                                 float* __restrict__ hs,   // [SEQ*32][512]
                                                 unsigned int* __restrict__ ctrs) {
  const int wg = blockIdx.x;
  const int dir = (wg >= SCAN_WGS) ? 1 : 0;
  const int wgl = wg - dir * SCAN_WGS;
  const float* __restrict__ pre = dir ? pre_b : pre_f;
  const float* __restrict__ whh = dir ? whh_b : whh_f;
  unsigned int* ctr = ctrs + dir * 32;   // cacheline-separated counters
  const int dirOff = dir * 256;
  const int u0 = wgl * 4;

  __shared__ float wlds[16][256];  // Whh rows for this WG's 16 z-columns
  __shared__ float hbuf[32][260];  // h_prev staging (pad 260 to limit conflicts)
  __shared__ float zbuf[16][33];   // z exchange for gate combine
  __shared__ float cbuf[4][32];    // persistent cell state (unit, batch)

  const int tid = threadIdx.x;
#pragma unroll
  for (int r = 0; r < 4; ++r) {
    int flat = r * 1024 + tid * 4;
    int c = flat >> 8;
    int k = flat & 255;
    int gcol = ((c >> 2) << 8) + u0 + (c & 3);  // gate*256 + unit
    *(float4*)&wlds[c][k] = *(const float4*)(whh + (size_t)gcol * 256 + k);
  }
  const int b = tid & 31;
  const int tp = tid >> 5;
  const int c0 = tp, c1 = tp + 8;
  const int gc0 = ((c0 >> 2) << 8) + u0 + (c0 & 3);
  const int gc1 = ((c1 >> 2) << 8) + u0 + (c1 & 3);
  __syncthreads();

  const int sfirst = dir ? (SEQ - 1) : 0;
  float p0 = pre[((size_t)(sfirst * BATCH) + b) * 1024 + gc0];
  float p1 = pre[((size_t)(sfirst * BATCH) + b) * 1024 + gc1];

  for (int t = 0; t < SEQ; ++t) {
    const int s = dir ? (SEQ - 1 - t) : t;
    // prefetch next step's pre contribution (hides HBM/IC latency)
    float np0 = 0.f, np1 = 0.f;
    if (t + 1 < SEQ) {
      const int sn = dir ? (s - 1) : (s + 1);
      np0 = pre[((size_t)(sn * BATCH) + b) * 1024 + gc0];
      np1 = pre[((size_t)(sn * BATCH) + b) * 1024 + gc1];
    }
    float acc0 = p0, acc1 = p1;
    if (t > 0) {
      const int sp = dir ? (s + 1) : (s - 1);
      const float* hrow = hs + (size_t)(sp * BATCH) * 512 + dirOff;
#pragma unroll
      for (int r = 0; r < 32; ++r) {
        hbuf[r][tid] = __hip_atomic_load(hrow + r * 512 + tid,
                                         __ATOMIC_RELAXED, __HIP_MEMORY_SCOPE_AGENT);
      }
      __syncthreads();
#pragma unroll 8
      for (int k4 = 0; k4 < 64; ++k4) {
        float4 h4 = *(const float4*)&hbuf[b][k4 * 4];
        float4 w0 = *(const float4*)&wlds[c0][k4 * 4];
        float4 w1 = *(const float4*)&wlds[c1][k4 * 4];
        acc0 += h4.x * w0.x; acc0 += h4.y * w0.y; acc0 += h4.z * w0.z; acc0 += h4.w * w0.w;
        acc1 += h4.x * w1.x; acc1 += h4.y * w1.y; acc1 += h4.z * w1.z; acc1 += h4.w * w1.w;
      }
    }
    zbuf[c0][b] = acc0;
    zbuf[c1][b] = acc1;
    __syncthreads();
    if (tid < 128) {
      const int u = tid & 3;
      const int bb = tid >> 2;
      float zi = zbuf[u][bb];
      float zf = zbuf[4 + u][bb];
      float zg = zbuf[8 + u][bb];
      float zo = zbuf[12 + u][bb];
      float cp = (t == 0) ? 0.f : cbuf[u][bb];
      float cn = sigm(zf) * cp + sigm(zi) * tanh_fast(zg);
      float hn = sigm(zo) * tanh_fast(cn);
      cbuf[u][bb] = cn;
      __hip_atomic_store(hs + ((size_t)(s * BATCH) + bb) * 512 + dirOff + u0 + u, hn,
                         __ATOMIC_RELAXED, __HIP_MEMORY_SCOPE_AGENT);
    }
    __threadfence();      // drain stores device-wide before signaling
    __syncthreads();
    if (tid == 0) {
      __hip_atomic_fetch_add(ctr, 1u, __ATOMIC_RELAXED, __HIP_MEMORY_SCOPE_AGENT);
      const unsigned int target = (unsigned int)SCAN_WGS * (unsigned int)(t + 1);
      while (__hip_atomic_load(ctr, __ATOMIC_RELAXED, __HIP_MEMORY_SCOPE_AGENT) < target) {
        __builtin_amdgcn_s_sleep(2);
      }
    }
    __syncthreads();
    p0 = np0; p1 = np1;
  }
}

// ---------------- attention: per time-step s, scores over the batch dim ----------------
// att[:, 0:512] already holds w = h1 @ attW^T (from gemm). Writes g into att[:, 512:1024].
__global__ __launch_bounds__(256) void attention_kernel(const float* __restrict__ h1s,
                                                        float* __restrict__ att) {
  const int s = blockIdx.x;
  __shared__ float wl[32][512];   // w rows
  __shared__ float xT[512][36];   // x transposed (pad 36 keeps float4 alignment)
  __shared__ float sc[32][33];    // scores / weights
  const int tid = threadIdx.x;
#pragma unroll
  for (int r = 0; r < 16; ++r) {
    int flat = r * 1024 + tid * 4;
    int bb = flat >> 9;
    int d = flat & 511;
    float4 wv = *(const float4*)(att + ((size_t)(s * BATCH) + bb) * 1024 + d);
    *(float4*)&wl[bb][d] = wv;
    float4 xv = *(const float4*)(h1s + ((size_t)(s * BATCH) + bb) * 512 + d);
    xT[d + 0][bb] = xv.x; xT[d + 1][bb] = xv.y; xT[d + 2][bb] = xv.z; xT[d + 3][bb] = xv.w;
  }
  __syncthreads();
  {
    const int i = tid >> 3;
    const int j0 = (tid & 7) << 2;
    float a0 = 0.f, a1 = 0.f, a2 = 0.f, a3 = 0.f;
    for (int k = 0; k < 512; ++k) {
      float wv = wl[i][k];
      float4 x4 = *(const float4*)&xT[k][j0];
      a0 += wv * x4.x; a1 += wv * x4.y; a2 += wv * x4.z; a3 += wv * x4.w;
    }
    sc[i][j0 + 0] = a0; sc[i][j0 + 1] = a1; sc[i][j0 + 2] = a2; sc[i][j0 + 3] = a3;
  }
  __syncthreads();
  if (tid < 32) {
    float m = -3.4e38f;
    for (int j = 0; j < 32; ++j) m = fmaxf(m, sc[tid][j]);
    float sum = 0.f;
    for (int j = 0; j < 32; ++j) { float ev = __expf(sc[tid][j] - m); sc[tid][j] = ev; sum += ev; }
    float inv = 1.0f / sum;
    for (int j = 0; j < 32; ++j) sc[tid][j] *= inv;
  }
  __syncthreads();
  {
    const int i = tid >> 3;
    const int dq = tid & 7;
#pragma unroll
    for (int rep = 0; rep < 8; ++rep) {
      const int d0 = dq * 64 + rep * 8;
      float g0 = 0.f, g1 = 0.f, g2 = 0.f, g3 = 0.f, g4 = 0.f, g5 = 0.f, g6 = 0.f, g7 = 0.f;
      for (int j = 0; j < 32; ++j) {
        float wt = sc[i][j];
        g0 += wt * xT[d0 + 0][j]; g1 += wt * xT[d0 + 1][j];
        g2 += wt * xT[d0 + 2][j]; g3 += wt * xT[d0 + 3][j];
        g4 += wt * xT[d0 + 4][j]; g5 += wt * xT[d0 + 5][j];
        g6 += wt * xT[d0 + 6][j]; g7 += wt * xT[d0 + 7][j];
      }
      float* o = att + ((size_t)(s * BATCH) + i) * 1024 + 512 + d0;
      *(float4*)(o) = make_float4(g0, g1, g2, g3);
      *(float4*)(o + 4) = make_float4(g4, g5, g6, g7);
    }
  }
}

// ---------------- Viterbi decode: one block per batch element ----------------
__global__ __launch_bounds__(64) void viterbi_kernel(const float* __restrict__ feats,
                                                     const float* __restrict__ trans,
                                                     int* __restrict__ out) {
  const int b = blockIdx.x;
  __shared__ float tl[NTAG][NTAG];
  __shared__ float fv[2][NTAG];
  __shared__ unsigned char bp[SEQ][NTAG];
  const int tid = threadIdx.x;
  for (int i = tid; i < NTAG * NTAG; i += 64) tl[i / NTAG][i % NTAG] = trans[i];
  if (tid < NTAG) fv[0][tid] = (tid == 10) ? 0.f : -10000.f;
  __syncthreads();
  for (int t = 0; t < SEQ; ++t) {
    const int cur = t & 1;
    if (tid < NTAG) {
      float m = -3.4e38f;
      int arg = 0;
      for (int p = 0; p < NTAG; ++p) {
        float v = fv[cur][p] + tl[tid][p];
        if (v > m) { m = v; arg = p; }   // strict > == first-max (matches jnp.argmax)
      }
      bp[t][tid] = (unsigned char)arg;
      fv[cur ^ 1][tid] = m + feats[((size_t)t * BATCH + b) * NTAG + tid];
    }
    __syncthreads();
  }
  if (tid == 0) {
    float m = -3.4e38f;
    int tag = 0;
    for (int p = 0; p < NTAG; ++p) {
      float v = fv[0][p] + tl[STOP_TAG][p];   // after 512 steps final fv is in fv[0]
      if (v > m) { m = v; tag = p; }
    }
    for (int t = SEQ - 1; t >= 0; --t) {
      out[b * SEQ + t] = tag;
      tag = bp[t][tag];
    }
  }
}

// ---------------- launch ----------------
extern "C" void kernel_launch(void* const* d_in, const int* in_sizes, int n_in,
                              void* d_out, int out_size, void* d_ws, size_t ws_size,
                              hipStream_t stream) {
  const int* inputs = (const int*)d_in[0];
  const float* emb = (const float*)d_in[1];
  const float* w1f_ih = (const float*)d_in[2];
  const float* w1f_hh = (const float*)d_in[3];
  const float* b1f_ih = (const float*)d_in[4];
  const float* b1f_hh = (const float*)d_in[5];
  const float* w1b_ih = (const float*)d_in[6];
  const float* w1b_hh = (const float*)d_in[7];
  const float* b1b_ih = (const float*)d_in[8];
  const float* b1b_hh = (const float*)d_in[9];
  const float* attW = (const float*)d_in[10];
  const float* w2f_ih = (const float*)d_in[11];
  const float* w2f_hh = (const float*)d_in[12];
  const float* b2f_ih = (const float*)d_in[13];
  const float* b2f_hh = (const float*)d_in[14];
  const float* w2b_ih = (const float*)d_in[15];
  const float* w2b_hh = (const float*)d_in[16];
  const float* b2b_ih = (const float*)d_in[17];
  const float* b2b_hh = (const float*)d_in[18];
  const float* h2t_W = (const float*)d_in[19];
  const float* h2t_b = (const float*)d_in[20];
  const float* trans = (const float*)d_in[21];

  float* ws = (float*)d_ws;
  float* preF = ws;                         // 16,777,216 f  (L1 pre fwd; reused L2)
  float* preB = ws + 16777216;              // 16,777,216 f  (L1 pre bwd; reused L2)
  float* h1s  = ws + 33554432;              //  8,388,608 f  (L1 hidden; reused as h2s)
  float* att  = ws + 41943040;              // 16,777,216 f  ([w|g] concat)
  float* x0   = ws + 58720256;              //  4,194,304 f  (embeddings; reused as feats)
  float* feats = x0;
  unsigned int* ctrs = (unsigned int*)(ws + 62914560);  // 128 uints
  int* out = (int*)d_out;

  hipMemsetAsync(ctrs, 0, 512, stream);
  embed_kernel<<<SEQ * BATCH, 64, 0, stream>>>(inputs, emb, x0);
  gemm_nt<<<dim3(256, 16), 256, 0, stream>>>(x0, w1f_ih, b1f_ih, b1f_hh, preF, 16384, 1024, 256, 1024);
  gemm_nt<<<dim3(256, 16), 256, 0, stream>>>(x0, w1b_ih, b1b_ih, b1b_hh, preB, 16384, 1024, 256, 1024);
  lstm_scan<<<2 * SCAN_WGS, 256, 0, stream>>>(preF, preB, w1f_hh, w1b_hh, h1s, ctrs);
  gemm_nt<<<dim3(256, 8), 256, 0, stream>>>(h1s, attW, nullptr, nullptr, att, 16384, 512, 512, 1024);
  attention_kernel<<<SEQ, 256, 0, stream>>>(h1s, att);
  gemm_nt<<<dim3(256, 16), 256, 0, stream>>>(att, w2f_ih, b2f_ih, b2f_hh, preF, 16384, 1024, 1024, 1024);
  gemm_nt<<<dim3(256, 16), 256, 0, stream>>>(att, w2b_ih, b2b_ih, b2b_hh, preB, 16384, 1024, 1024, 1024);
  lstm_scan<<<2 * SCAN_WGS, 256, 0, stream>>>(preF, preB, w2f_hh, w2b_hh, h1s, ctrs + 64);
  gemm_nt<<<dim3(256, 1), 256, 0, stream>>>(h1s, h2t_W, h2t_b, nullptr, feats, 16384, 12, 512, 12);
  viterbi_kernel<<<BATCH, 64, 0, stream>>>(feats, trans, out);
}

// Round 3
// 13719.342 us; speedup vs baseline: 1.5017x; 1.5017x over previous
//
#include <hip/hip_runtime.h>

#define SEQ 512
#define BATCH 32
#define NTAG 12
#define STOP_TAG 11
#define WC 64   // k-rows cached in VGPRs per thread (WC*4 VGPRs)

static __device__ __forceinline__ float sigm(float x) {
  return 1.0f / (1.0f + __expf(-x));
}
static __device__ __forceinline__ float tanh_fast(float x) {
  // exact identity: tanh(x) = 1 - 2/(exp(2x)+1); error only from __expf ulp
  return 1.0f - 2.0f / (1.0f + __expf(2.0f * x));
}
static __device__ __forceinline__ void fma4(float4& acc, float s, const float4& w) {
  acc.x += s * w.x; acc.y += s * w.y; acc.z += s * w.z; acc.w += s * w.w;
}

// ---------------- embedding gather: x0[s*32+b][e] = emb[inputs[b][s]][e] ----------------
__global__ __launch_bounds__(64) void embed_kernel(const int* __restrict__ inputs,
                                                   const float* __restrict__ emb,
                                                   float* __restrict__ x0) {
  const int sb = blockIdx.x;          // s*32 + b
  const int s = sb >> 5, b = sb & 31;
  const int tok = inputs[b * SEQ + s];
  const float4* src = (const float4*)(emb + (size_t)tok * 256);
  float4* dst = (float4*)(x0 + (size_t)sb * 256);
  dst[threadIdx.x] = src[threadIdx.x];
}

// ---------------- transpose Whh [1024][256] -> WhhT [256][1024] ----------------
__global__ __launch_bounds__(256) void transpose_whh(const float* __restrict__ in,
                                                     float* __restrict__ out) {
  __shared__ float tile[32][33];
  const int tx = threadIdx.x & 31, ty = threadIdx.x >> 5;  // 32 x 8
  const int jb = blockIdx.x * 32;   // over 1024
  const int kb = blockIdx.y * 32;   // over 256
#pragma unroll
  for (int r = 0; r < 32; r += 8)
    tile[ty + r][tx] = in[(size_t)(jb + ty + r) * 256 + kb + tx];
  __syncthreads();
#pragma unroll
  for (int r = 0; r < 32; r += 8)
    out[(size_t)(kb + ty + r) * 1024 + jb + tx] = tile[tx][ty + r];
}

// ---------------- generic fp32 GEMM: C[M][N] = A[M][K] @ W[N][K]^T (+b1+b2) ----------------
__global__ __launch_bounds__(256) void gemm_nt(const float* __restrict__ A,
                                               const float* __restrict__ W,
                                               const float* __restrict__ b1,
                                               const float* __restrict__ b2,
                                               float* __restrict__ C,
                                               int M, int N, int K, int ldc) {
  __shared__ float aT[16][68];
  __shared__ float wT[16][68];
  const int tid = threadIdx.x;
  const int bm = blockIdx.x * 64;
  const int bn = blockIdx.y * 64;
  const int tm = ((tid >> 4) & 15) << 2;
  const int tn = (tid & 15) << 2;
  const int lr = tid >> 2;
  const int lk = (tid & 3) << 2;
  const bool wok = (bn + lr) < N;
  float acc00 = 0.f, acc01 = 0.f, acc02 = 0.f, acc03 = 0.f;
  float acc10 = 0.f, acc11 = 0.f, acc12 = 0.f, acc13 = 0.f;
  float acc20 = 0.f, acc21 = 0.f, acc22 = 0.f, acc23 = 0.f;
  float acc30 = 0.f, acc31 = 0.f, acc32 = 0.f, acc33 = 0.f;
  for (int k0 = 0; k0 < K; k0 += 16) {
    float4 av = *(const float4*)(A + (size_t)(bm + lr) * K + k0 + lk);
    float4 wv = make_float4(0.f, 0.f, 0.f, 0.f);
    if (wok) wv = *(const float4*)(W + (size_t)(bn + lr) * K + k0 + lk);
    aT[lk + 0][lr] = av.x; aT[lk + 1][lr] = av.y; aT[lk + 2][lr] = av.z; aT[lk + 3][lr] = av.w;
    wT[lk + 0][lr] = wv.x; wT[lk + 1][lr] = wv.y; wT[lk + 2][lr] = wv.z; wT[lk + 3][lr] = wv.w;
    __syncthreads();
#pragma unroll
    for (int k = 0; k < 16; ++k) {
      float4 a4 = *(const float4*)&aT[k][tm];
      float4 w4 = *(const float4*)&wT[k][tn];
      acc00 += a4.x * w4.x; acc01 += a4.x * w4.y; acc02 += a4.x * w4.z; acc03 += a4.x * w4.w;
      acc10 += a4.y * w4.x; acc11 += a4.y * w4.y; acc12 += a4.y * w4.z; acc13 += a4.y * w4.w;
      acc20 += a4.z * w4.x; acc21 += a4.z * w4.y; acc22 += a4.z * w4.z; acc23 += a4.z * w4.w;
      acc30 += a4.w * w4.x; acc31 += a4.w * w4.y; acc32 += a4.w * w4.z; acc33 += a4.w * w4.w;
    }
    __syncthreads();
  }
  float r[4][4] = {{acc00, acc01, acc02, acc03},
                   {acc10, acc11, acc12, acc13},
                   {acc20, acc21, acc22, acc23},
                   {acc30, acc31, acc32, acc33}};
#pragma unroll
  for (int i = 0; i < 4; ++i) {
#pragma unroll
    for (int j = 0; j < 4; ++j) {
      int n = bn + tn + j;
      if (n < N) {
        float v = r[i][j];
        if (b1) v += b1[n];
        if (b2) v += b2[n];
        C[(size_t)(bm + tm + i) * ldc + n] = v;
      }
    }
  }
}

// ---------------- batch-parallel BiLSTM scan: zero cross-WG communication ----------------
// grid = 64: wg < 32 -> forward (b = wg), wg >= 32 -> backward (b = wg-32).
// Each WG owns one (batch, dir) pair; h and c live in LDS/regs. WhhT streamed from L2
// (first WC k-rows cached per-thread in VGPRs).
__global__ __launch_bounds__(256, 1) void lstm_scan(const float* __restrict__ pre_f,
                                                    const float* __restrict__ pre_b,
                                                    const float* __restrict__ whhT_f,
                                                    const float* __restrict__ whhT_b,
                                                    float* __restrict__ hs) {  // [SEQ*32][512]
  const int wg = blockIdx.x;
  const int dir = (wg >= BATCH) ? 1 : 0;
  const int b = wg - dir * BATCH;
  const float* __restrict__ pre = dir ? pre_b : pre_f;
  const float* __restrict__ whhT = dir ? whhT_b : whhT_f;
  const int dirOff = dir * 256;

  __shared__ float hbuf[2][256];
  __shared__ float zbuf[1024];

  const int tid = threadIdx.x;
  const int j0 = tid * 4;            // 4 consecutive z-columns per thread
  const float* __restrict__ wp = whhT + j0;

  // VGPR-cache the first WC k-rows of this thread's 4 columns
  float4 wc[WC];
#pragma unroll
  for (int k = 0; k < WC; ++k) wc[k] = *(const float4*)(wp + (size_t)k * 1024);

  float c_reg = 0.0f;                // thread tid owns cell state of unit tid
  int cur = 0;

  for (int t = 0; t < SEQ; ++t) {
    const int s = dir ? (SEQ - 1 - t) : t;
    float4 acc = *(const float4*)(pre + ((size_t)(s * BATCH) + b) * 1024 + j0);
    if (t > 0) {
      const float4* __restrict__ h4 = (const float4*)hbuf[cur];
#pragma unroll
      for (int k4 = 0; k4 < WC / 4; ++k4) {
        float4 hk = h4[k4];
        fma4(acc, hk.x, wc[4 * k4 + 0]);
        fma4(acc, hk.y, wc[4 * k4 + 1]);
        fma4(acc, hk.z, wc[4 * k4 + 2]);
        fma4(acc, hk.w, wc[4 * k4 + 3]);
      }
#pragma unroll 4
      for (int k4 = WC / 4; k4 < 64; ++k4) {
        float4 hk = h4[k4];
        float4 w0 = *(const float4*)(wp + (size_t)(4 * k4 + 0) * 1024);
        float4 w1 = *(const float4*)(wp + (size_t)(4 * k4 + 1) * 1024);
        float4 w2 = *(const float4*)(wp + (size_t)(4 * k4 + 2) * 1024);
        float4 w3 = *(const float4*)(wp + (size_t)(4 * k4 + 3) * 1024);
        fma4(acc, hk.x, w0);
        fma4(acc, hk.y, w1);
        fma4(acc, hk.z, w2);
        fma4(acc, hk.w, w3);
      }
    }
    *(float4*)&zbuf[j0] = acc;
    __syncthreads();
    // gate combine: unit u = tid
    {
      const float zi = zbuf[tid];
      const float zf = zbuf[256 + tid];
      const float zg = zbuf[512 + tid];
      const float zo = zbuf[768 + tid];
      c_reg = sigm(zf) * c_reg + sigm(zi) * tanh_fast(zg);
      const float h = sigm(zo) * tanh_fast(c_reg);
      hbuf[cur ^ 1][tid] = h;
      hs[((size_t)(s * BATCH) + b) * 512 + dirOff + tid] = h;
    }
    __syncthreads();
    cur ^= 1;
  }
}

// ---------------- attention: per time-step s, scores over the batch dim ----------------
__global__ __launch_bounds__(256) void attention_kernel(const float* __restrict__ h1s,
                                                        float* __restrict__ att) {
  const int s = blockIdx.x;
  __shared__ float wl[32][512];   // w rows
  __shared__ float xT[512][36];   // x transposed
  __shared__ float sc[32][33];    // scores / weights
  const int tid = threadIdx.x;
#pragma unroll
  for (int r = 0; r < 16; ++r) {
    int flat = r * 1024 + tid * 4;
    int bb = flat >> 9;
    int d = flat & 511;
    float4 wv = *(const float4*)(att + ((size_t)(s * BATCH) + bb) * 1024 + d);
    *(float4*)&wl[bb][d] = wv;
    float4 xv = *(const float4*)(h1s + ((size_t)(s * BATCH) + bb) * 512 + d);
    xT[d + 0][bb] = xv.x; xT[d + 1][bb] = xv.y; xT[d + 2][bb] = xv.z; xT[d + 3][bb] = xv.w;
  }
  __syncthreads();
  {
    const int i = tid >> 3;
    const int j0 = (tid & 7) << 2;
    float a0 = 0.f, a1 = 0.f, a2 = 0.f, a3 = 0.f;
    for (int k = 0; k < 512; ++k) {
      float wv = wl[i][k];
      float4 x4 = *(const float4*)&xT[k][j0];
      a0 += wv * x4.x; a1 += wv * x4.y; a2 += wv * x4.z; a3 += wv * x4.w;
    }
    sc[i][j0 + 0] = a0; sc[i][j0 + 1] = a1; sc[i][j0 + 2] = a2; sc[i][j0 + 3] = a3;
  }
  __syncthreads();
  if (tid < 32) {
    float m = -3.4e38f;
    for (int j = 0; j < 32; ++j) m = fmaxf(m, sc[tid][j]);
    float sum = 0.f;
    for (int j = 0; j < 32; ++j) { float ev = __expf(sc[tid][j] - m); sc[tid][j] = ev; sum += ev; }
    float inv = 1.0f / sum;
    for (int j = 0; j < 32; ++j) sc[tid][j] *= inv;
  }
  __syncthreads();
  {
    const int i = tid >> 3;
    const int dq = tid & 7;
#pragma unroll
    for (int rep = 0; rep < 8; ++rep) {
      const int d0 = dq * 64 + rep * 8;
      float g0 = 0.f, g1 = 0.f, g2 = 0.f, g3 = 0.f, g4 = 0.f, g5 = 0.f, g6 = 0.f, g7 = 0.f;
      for (int j = 0; j < 32; ++j) {
        float wt = sc[i][j];
        g0 += wt * xT[d0 + 0][j]; g1 += wt * xT[d0 + 1][j];
        g2 += wt * xT[d0 + 2][j]; g3 += wt * xT[d0 + 3][j];
        g4 += wt * xT[d0 + 4][j]; g5 += wt * xT[d0 + 5][j];
        g6 += wt * xT[d0 + 6][j]; g7 += wt * xT[d0 + 7][j];
      }
      float* o = att + ((size_t)(s * BATCH) + i) * 1024 + 512 + d0;
      *(float4*)(o) = make_float4(g0, g1, g2, g3);
      *(float4*)(o + 4) = make_float4(g4, g5, g6, g7);
    }
  }
}

// ---------------- Viterbi decode: one block per batch element ----------------
__global__ __launch_bounds__(64) void viterbi_kernel(const float* __restrict__ feats,
                                                     const float* __restrict__ trans,
                                                     int* __restrict__ out) {
  const int b = blockIdx.x;
  __shared__ float tl[NTAG][NTAG];
  __shared__ float fv[2][NTAG];
  __shared__ unsigned char bp[SEQ][NTAG];
  const int tid = threadIdx.x;
  for (int i = tid; i < NTAG * NTAG; i += 64) tl[i / NTAG][i % NTAG] = trans[i];
  if (tid < NTAG) fv[0][tid] = (tid == 10) ? 0.f : -10000.f;
  __syncthreads();
  for (int t = 0; t < SEQ; ++t) {
    const int cur = t & 1;
    if (tid < NTAG) {
      float m = -3.4e38f;
      int arg = 0;
      for (int p = 0; p < NTAG; ++p) {
        float v = fv[cur][p] + tl[tid][p];
        if (v > m) { m = v; arg = p; }   // strict > == first-max (matches jnp.argmax)
      }
      bp[t][tid] = (unsigned char)arg;
      fv[cur ^ 1][tid] = m + feats[((size_t)t * BATCH + b) * NTAG + tid];
    }
    __syncthreads();
  }
  if (tid == 0) {
    float m = -3.4e38f;
    int tag = 0;
    for (int p = 0; p < NTAG; ++p) {
      float v = fv[0][p] + tl[STOP_TAG][p];
      if (v > m) { m = v; tag = p; }
    }
    for (int t = SEQ - 1; t >= 0; --t) {
      out[b * SEQ + t] = tag;
      tag = bp[t][tag];
    }
  }
}

// ---------------- launch ----------------
extern "C" void kernel_launch(void* const* d_in, const int* in_sizes, int n_in,
                              void* d_out, int out_size, void* d_ws, size_t ws_size,
                              hipStream_t stream) {
  const int* inputs = (const int*)d_in[0];
  const float* emb = (const float*)d_in[1];
  const float* w1f_ih = (const float*)d_in[2];
  const float* w1f_hh = (const float*)d_in[3];
  const float* b1f_ih = (const float*)d_in[4];
  const float* b1f_hh = (const float*)d_in[5];
  const float* w1b_ih = (const float*)d_in[6];
  const float* w1b_hh = (const float*)d_in[7];
  const float* b1b_ih = (const float*)d_in[8];
  const float* b1b_hh = (const float*)d_in[9];
  const float* attW = (const float*)d_in[10];
  const float* w2f_ih = (const float*)d_in[11];
  const float* w2f_hh = (const float*)d_in[12];
  const float* b2f_ih = (const float*)d_in[13];
  const float* b2f_hh = (const float*)d_in[14];
  const float* w2b_ih = (const float*)d_in[15];
  const float* w2b_hh = (const float*)d_in[16];
  const float* b2b_ih = (const float*)d_in[17];
  const float* b2b_hh = (const float*)d_in[18];
  const float* h2t_W = (const float*)d_in[19];
  const float* h2t_b = (const float*)d_in[20];
  const float* trans = (const float*)d_in[21];

  float* ws = (float*)d_ws;
  float* preF = ws;                         // 16,777,216 f
  float* preB = ws + 16777216;              // 16,777,216 f
  float* h1s  = ws + 33554432;              //  8,388,608 f (L1 hidden; reused as h2s)
  float* att  = ws + 41943040;              // 16,777,216 f ([w|g]); head doubles as whhT1 before att-GEMM
  float* x0   = ws + 58720256;              //  4,194,304 f (embeddings; reused as whhT2, then feats)
  float* feats = x0;
  float* whhT1f = att;                      // 262,144 f each — dead once att-GEMM runs
  float* whhT1b = att + 262144;
  float* whhT2f = x0;                       // x0 dead after L1 pre-GEMMs
  float* whhT2b = x0 + 262144;
  int* out = (int*)d_out;

  embed_kernel<<<SEQ * BATCH, 64, 0, stream>>>(inputs, emb, x0);
  transpose_whh<<<dim3(32, 8), 256, 0, stream>>>(w1f_hh, whhT1f);
  transpose_whh<<<dim3(32, 8), 256, 0, stream>>>(w1b_hh, whhT1b);
  gemm_nt<<<dim3(256, 16), 256, 0, stream>>>(x0, w1f_ih, b1f_ih, b1f_hh, preF, 16384, 1024, 256, 1024);
  gemm_nt<<<dim3(256, 16), 256, 0, stream>>>(x0, w1b_ih, b1b_ih, b1b_hh, preB, 16384, 1024, 256, 1024);
  lstm_scan<<<2 * BATCH, 256, 0, stream>>>(preF, preB, whhT1f, whhT1b, h1s);
  // x0 (embeddings) now dead -> stage layer-2 WhhT there
  transpose_whh<<<dim3(32, 8), 256, 0, stream>>>(w2f_hh, whhT2f);
  transpose_whh<<<dim3(32, 8), 256, 0, stream>>>(w2b_hh, whhT2b);
  gemm_nt<<<dim3(256, 8), 256, 0, stream>>>(h1s, attW, nullptr, nullptr, att, 16384, 512, 512, 1024);
  attention_kernel<<<SEQ, 256, 0, stream>>>(h1s, att);
  gemm_nt<<<dim3(256, 16), 256, 0, stream>>>(att, w2f_ih, b2f_ih, b2f_hh, preF, 16384, 1024, 1024, 1024);
  gemm_nt<<<dim3(256, 16), 256, 0, stream>>>(att, w2b_ih, b2b_ih, b2b_hh, preB, 16384, 1024, 1024, 1024);
  lstm_scan<<<2 * BATCH, 256, 0, stream>>>(preF, preB, whhT2f, whhT2b, h1s);
  gemm_nt<<<dim3(256, 1), 256, 0, stream>>>(h1s, h2t_W, h2t_b, nullptr, feats, 16384, 12, 512, 12);
  viterbi_kernel<<<BATCH, 64, 0, stream>>>(feats, trans, out);
}